// Round 16
// baseline (398.710 us; speedup 1.0000x reference)
//
#include <hip/hip_runtime.h>
#include <stdint.h>

// Problem constants (fixed by reference: L=1024, B=8, D=2048)
#define L_SEQ 1024
#define BATCH 8
#define DIM   2048
#define GM    8192   // L*B
#define GN    6144   // 3*D
#define GK    2048   // D
#define SCALE_X 1.7320508075688772f  // sqrt(1 + 2*exp(0))

// GEMM geometry: 256x256 tile, 8 waves (2M x 4N), k-ring of 4 slices of 32
#define BM 256
#define BN 256
#define BKC 32

using bf16x8  = __attribute__((ext_vector_type(8))) __bf16;
using floatx4 = __attribute__((ext_vector_type(4))) float;

__device__ __forceinline__ unsigned short f2bf(float f) {
  unsigned u = __float_as_uint(f);
  u += 0x7FFFu + ((u >> 16) & 1u);   // round-to-nearest-even
  return (unsigned short)(u >> 16);
}
__device__ __forceinline__ float sigmoidf_fast(float z) {
  return __builtin_amdgcn_rcpf(1.0f + __expf(-z));
}
__device__ __forceinline__ void async16(const unsigned short* g, unsigned short* l) {
  __builtin_amdgcn_global_load_lds(
      (__attribute__((address_space(1))) unsigned int*)g,
      (__attribute__((address_space(3))) unsigned int*)l,
      16, 0, 0);
}

// ------------- fused prep: transpose-cast W -> Bt  +  cast x -> A (bf16) --------
// THIS ROUND: transpose tiles widened to 64k x 256n. W row reads are 1-KB
// contiguous (vs 256-B segments at 24-KB stride before -- 4x DRAM page
// locality on the ~50 MB W stream). LDS 64 KB/block (2 blocks/CU). Each
// thread packs ONE n-column (64 ds_read_b32, bank = jl&31 across lanes ->
// 2-way, free) and writes one full 128-B line of Bt. np mapping unchanged ->
// Bt bit-identical.
// Blocks [0, 768): transpose tiles (n-tile = blk%24 [256 cols], k-tile =
// blk/24 [64 rows]). Blocks [768, 4864): grid-stride streaming cast of x.
// W col n = 3d+j -> j==0: Bt row d (u0 plane); j>0: Bt row DIM + 2d + (j-1).
__global__ __launch_bounds__(256) void prep_kernel(const float4* __restrict__ xin,
                                                   unsigned short* __restrict__ Aout,
                                                   const float* __restrict__ W,
                                                   unsigned short* __restrict__ Bt) {
  __shared__ float tile[64][256];  // 64 KB
  const int blk = blockIdx.x;
  if (blk < 768) {
    const int lane = threadIdx.x & 63, ty = threadIdx.x >> 6;  // 4 row-groups
    const int n0 = (blk % 24) * 256;
    const int k0 = (blk / 24) * 64;
#pragma unroll
    for (int rr = 0; rr < 16; ++rr) {
      const int row = rr * 4 + ty;
      const float4 v = *(const float4*)&W[(size_t)(k0 + row) * GN + n0 + lane * 4];
      *(float4*)&tile[row][lane * 4] = v;
    }
    __syncthreads();
    const int jl = threadIdx.x;              // n-column 0..255
    const int n = n0 + jl;
    const int dq = n / 3, j3 = n - 3 * dq;
    const int np = (j3 == 0) ? dq : (DIM + 2 * dq + (j3 - 1));
    union { unsigned short s[64]; uint4 q[8]; } o;
#pragma unroll
    for (int k = 0; k < 64; ++k) o.s[k] = f2bf(tile[k][jl]);
    uint4* dst = (uint4*)&Bt[(size_t)np * GK + k0];
#pragma unroll
    for (int q8 = 0; q8 < 8; ++q8) dst[q8] = o.q[q8];
  } else {
    const int n4 = (GM * GK) / 4;
    for (int i = (blk - 768) * 256 + threadIdx.x; i < n4; i += 4096 * 256) {
      float4 v = xin[i];
      union { unsigned short s[4]; unsigned long long ll; } o;
      o.s[0] = f2bf(v.x); o.s[1] = f2bf(v.y); o.s[2] = f2bf(v.z); o.s[3] = f2bf(v.w);
      *(unsigned long long*)&Aout[(size_t)i * 4] = o.ll;
    }
  }
}

// ---------------- GEMM: U = A(GM x GK) * Bt(GN x GK)^T, bf16 out ----------------
// Round-4/8 structure verbatim (best measured: 197-200us, MfmaUtil 46, conf 0).
// Merged-body attempts (r5, r13) and BN=384 (r11) all regressed -> this is the
// structure's floor. 256x256 tile, 8 waves (2M x 4N), per-wave 128x64 = 8x4
// reps of 16x16x32 MFMA. LDS = ring of 4 k-slices (k=32): 128 KB, 1 blk/CU.
// Per chunk c: WAITV(8) ; BAR0 ; R0(8 ds_read) + stageA(c+3) ; BAR1 ; lgkm0 ;
// 16 MFMA ; BAR2 ; R1(4 ds_read) + stageB(c+3) ; BAR3 ; lgkm0 ; 16 MFMA.
// WAITV(8) waits only chunk c's loads (issued 3 chunks earlier -> free).
// LDS swizzle: 16B slot S(row,s) = (row>>1)*8 + (((row&1)*4+s)^((row>>1)&7));
// read-side XOR + inverse-permuted global source (LDS dest lane-linear).
// XCD-rectangle swizzle: 768 = 8 XCD x 3 rounds x (4y x 8x).

#define WAITV(N) asm volatile("s_waitcnt vmcnt(" #N ")" ::: "memory")
#define LGKM0 asm volatile("s_waitcnt lgkmcnt(0)" ::: "memory"); \
              __builtin_amdgcn_sched_barrier(0)

#define CHUNK(cexpr, SL, DOSTAGE)                                             \
  {                                                                           \
    __builtin_amdgcn_s_barrier();  /* BAR0 */                                 \
    __builtin_amdgcn_sched_barrier(0);                                        \
    const int c_ = (cexpr);                                                   \
    const char* aB_ = AsB + (SL) * 16384;                                     \
    const char* bB_ = BsB + (SL) * 16384;                                     \
    bf16x8 bF[4], aF[4];                                                      \
    _Pragma("unroll") for (int nt = 0; nt < 4; ++nt)                          \
        bF[nt] = *(const bf16x8*)(bB_ + SB0 + nt * 1024);                     \
    _Pragma("unroll") for (int mt = 0; mt < 4; ++mt)                          \
        aF[mt] = *(const bf16x8*)(aB_ + SA0 + mt * 1024);                     \
    if (DOSTAGE) {                                                            \
      unsigned short* ad_ = (unsigned short*)(AsL + ((c_ + 3) & 3) * 16384);  \
      const int ko_ = (c_ + 3) * BKC;                                         \
      async16(aG0 + ko_, ad_ + L0 * 8);                                       \
      async16(aG1 + ko_, ad_ + L1 * 8);                                       \
    }                                                                         \
    __builtin_amdgcn_sched_barrier(0);                                        \
    __builtin_amdgcn_s_barrier();  /* BAR1: read-burst | MFMA-burst fence */  \
    LGKM0;                                                                    \
    __builtin_amdgcn_s_setprio(1);                                            \
    _Pragma("unroll") for (int mt = 0; mt < 4; ++mt)                          \
      _Pragma("unroll") for (int nt = 0; nt < 4; ++nt)                        \
        acc[mt][nt] = __builtin_amdgcn_mfma_f32_16x16x32_bf16(                \
            aF[mt], bF[nt], acc[mt][nt], 0, 0, 0);                            \
    __builtin_amdgcn_s_setprio(0);                                            \
    __builtin_amdgcn_sched_barrier(0);                                        \
    __builtin_amdgcn_s_barrier();  /* BAR2 */                                 \
    _Pragma("unroll") for (int mt = 0; mt < 4; ++mt)                          \
        aF[mt] = *(const bf16x8*)(aB_ + SA0 + 4096 + mt * 1024);              \
    if (DOSTAGE) {                                                            \
      unsigned short* bd_ = (unsigned short*)(BsL + ((c_ + 3) & 3) * 16384);  \
      const int ko_ = (c_ + 3) * BKC;                                        \
      async16(bG0 + ko_, bd_ + L0 * 8);                                       \
      async16(bG1 + ko_, bd_ + L1 * 8);                                       \
    }                                                                         \
    __builtin_amdgcn_sched_barrier(0);                                        \
    __builtin_amdgcn_s_barrier();  /* BAR3 */                                 \
    LGKM0;                                                                    \
    __builtin_amdgcn_s_setprio(1);                                            \
    _Pragma("unroll") for (int mt = 0; mt < 4; ++mt)                          \
      _Pragma("unroll") for (int nt = 0; nt < 4; ++nt)                        \
        acc[mt + 4][nt] = __builtin_amdgcn_mfma_f32_16x16x32_bf16(            \
            aF[mt], bF[nt], acc[mt + 4][nt], 0, 0, 0);                        \
    __builtin_amdgcn_s_setprio(0);                                            \
    __builtin_amdgcn_sched_barrier(0);                                        \
  }

__global__ __launch_bounds__(512, 2) void gemm_kernel(const unsigned short* __restrict__ A,
                                                      const unsigned short* __restrict__ Bt,
                                                      unsigned short* __restrict__ U) {
  __shared__ alignas(16) unsigned short As[4][BM * BKC];  // 64 KB
  __shared__ alignas(16) unsigned short Bs[4][BN * BKC];  // 64 KB
  const int tid  = threadIdx.x;
  const int wave = tid >> 6, lane = tid & 63;
  const int quad = lane >> 4, lrow = lane & 15;
  const int wm = (wave >> 2) * 128;  // 2 M-waves
  const int wn = (wave & 3) * 64;    // 4 N-waves

  // XCD-rectangle swizzle: 768 blocks = 8 XCD x 3 rounds x 32 slots (4y x 8x)
  const int f    = blockIdx.y * (GN / BN) + blockIdx.x;
  const int xcd  = f & 7;
  const int slot = f >> 3;
  const int rnd  = slot >> 5;        // 0..2
  const int ss   = slot & 31;        // 0..31
  const int mBase = (4 * xcd + (ss & 3)) * BM;   // y-tile 0..31
  const int nBase = (8 * rnd + (ss >> 2)) * BN;  // x-tile 0..23

  floatx4 acc[8][4] = {};

  // staging: thread owns 16B slots L0=tid, L1=tid+512 of each slice (lane-linear
  // LDS dest). Invert swizzle to find the (row, k-slot) this slot must hold.
  const int L0 = tid, L1 = tid + 512;
  int r0, s0, r1, s1;
  { const int p = L0 >> 3, w = L0 & 7, v = w ^ (p & 7); r0 = 2 * p + (v >> 2); s0 = v & 3; }
  { const int p = L1 >> 3, w = L1 & 7, v = w ^ (p & 7); r1 = 2 * p + (v >> 2); s1 = v & 3; }
  const unsigned short* aG0 = A  + (size_t)(mBase + r0) * GK + s0 * 8;
  const unsigned short* aG1 = A  + (size_t)(mBase + r1) * GK + s1 * 8;
  const unsigned short* bG0 = Bt + (size_t)(nBase + r0) * GK + s0 * 8;
  const unsigned short* bG1 = Bt + (size_t)(nBase + r1) * GK + s1 * 8;

  // ds_read byte offsets within a slice (+16 rows = +1024 B)
  const int rA = wm + lrow;
  const int SA0 = (rA >> 1) * 128 + ((((rA & 1) * 4 + quad) ^ ((rA >> 1) & 7)) * 16);
  const int rB = wn + lrow;
  const int SB0 = (rB >> 1) * 128 + ((((rB & 1) * 4 + quad) ^ ((rB >> 1) & 7)) * 16);
  const char* AsB = (const char*)As;
  const char* BsB = (const char*)Bs;
  char* AsL = (char*)As;
  char* BsL = (char*)Bs;

  // prologue: stage chunks 0,1,2 (12 loads/thread in flight)
#pragma unroll
  for (int c = 0; c < 3; ++c) {
    unsigned short* ad = (unsigned short*)(AsL + c * 16384);
    unsigned short* bd = (unsigned short*)(BsL + c * 16384);
    async16(aG0 + c * BKC, ad + L0 * 8);
    async16(aG1 + c * BKC, ad + L1 * 8);
    async16(bG0 + c * BKC, bd + L0 * 8);
    async16(bG1 + c * BKC, bd + L1 * 8);
  }

  // main loop: chunks 0..59 (stage c+3), then peeled 60..63
#pragma unroll 1
  for (int cc = 0; cc < 15; ++cc) {
    const int cb = cc * 4;
#pragma unroll
    for (int j = 0; j < 4; ++j) {
      WAITV(8);
      CHUNK(cb + j, j, true);
    }
  }
  WAITV(8); CHUNK(60, 0, true);   // stages chunk 63
  WAITV(8); CHUNK(61, 1, false);
  WAITV(4); CHUNK(62, 2, false);
  WAITV(0); CHUNK(63, 3, false);

  // C/D layout: col = lane&15 (N), row = quad*4 + reg (M). Flat U: col = gn.
#pragma unroll
  for (int mt = 0; mt < 8; ++mt) {
    const int gm = mBase + wm + mt * 16 + quad * 4;
#pragma unroll
    for (int nt = 0; nt < 4; ++nt) {
      const int gn = nBase + wn + nt * 16 + lrow;
#pragma unroll
      for (int q = 0; q < 4; ++q)
        U[(size_t)(gm + q) * GN + gn] = f2bf(acc[mt][nt][q]);
    }
  }
}

// ------------- SRU scan: producer/consumer wave split over an LDS ring ----------
// r14 version verbatim (benched 392us, current best). 256 blocks x 128 threads.
// Wave 1 (producer): 4-slot x 16-step LDS ring, 8 global_load_lds dwordx4 per
// slot. WAITV(16) seals slot p+1; slot p+3 overwrites slot p-1.
// Wave 0 (consumer): hoists all 48 LDS reads of the phase into registers
// (static indexing) before the serial math loop, then runs the recurrence
// register-only. Same ops/order -> bit-identical output.
__global__ __launch_bounds__(128) void sru_scan_pc(const unsigned short* __restrict__ U,
                                                   const unsigned short* __restrict__ xbf,
                                                   const float* __restrict__ c0,
                                                   const float* __restrict__ wc,
                                                   const float* __restrict__ bias,
                                                   float* __restrict__ out) {
  __shared__ alignas(16) unsigned short Sm[4][4096];  // 4 slots x 8 KB
  const int tid  = threadIdx.x;
  const int wave = tid >> 6, lane = tid & 63;
  const int blk = blockIdx.x;
  const int b = blk >> 5, dch = blk & 31;
  const int d0 = dch * 64;

  constexpr size_t US  = (size_t)BATCH * GN;   // shorts per l-step (U)
  constexpr size_t XSs = (size_t)BATCH * DIM;  // shorts per l-step (x)
  constexpr int XS = BATCH * DIM;              // floats per l-step (out)

  if (wave == 1) {
    // ---------------- producer ----------------
    const int s8 = lane >> 3, c8 = lane & 7;    // 8-step groups (u0, x)
    const int s4 = lane >> 4, c16 = lane & 15;  // 4-step groups (u1u2)
    const unsigned short* u0g  = U   + (size_t)b * GN + d0 + c8 * 8 + (size_t)s8 * US;
    const unsigned short* u12g = U   + (size_t)b * GN + DIM + 2 * d0 + c16 * 8 + (size_t)s4 * US;
    const unsigned short* xg   = xbf + (size_t)b * DIM + d0 + c8 * 8 + (size_t)s8 * XSs;

#define STAGE_SLOT(SL, L0S)                                                   \
    {                                                                         \
      unsigned short* dst = &Sm[(SL)][0] + lane * 8;                          \
      const size_t l0_ = (size_t)(L0S);                                       \
      async16(u0g + l0_ * US, dst);              /* steps l0..l0+7   */       \
      async16(u0g + (l0_ + 8) * US, dst + 512);  /* steps l0+8..+15  */       \
      async16(u12g + l0_ * US, dst + 1024);      /* steps l0..l0+3   */       \
      async16(u12g + (l0_ + 4) * US, dst + 1536);                             \
      async16(u12g + (l0_ + 8) * US, dst + 2048);                             \
      async16(u12g + (l0_ + 12) * US, dst + 2560);                            \
      async16(xg + l0_ * XSs, dst + 3072);                                    \
      async16(xg + (l0_ + 8) * XSs, dst + 3584);                              \
    }

    // prologue: slots 0,1,2 (24 in flight); seal slot 0
    STAGE_SLOT(0, 0); STAGE_SLOT(1, 16); STAGE_SLOT(2, 32);
    WAITV(16);
#pragma unroll 1
    for (int p = 0; p < 64; ++p) {
      __builtin_amdgcn_s_barrier();
      __builtin_amdgcn_sched_barrier(0);
      if (p < 61) {
        STAGE_SLOT((p + 3) & 3, 16 * (p + 3));
        WAITV(16);           // seal slot p+1; keep p+2, p+3 in flight
      } else if (p == 61) {
        WAITV(8);            // seal slot 62
      } else if (p == 62) {
        WAITV(0);            // seal slot 63
      }
      __builtin_amdgcn_sched_barrier(0);
    }
#undef STAGE_SLOT
  } else {
    // ---------------- consumer ----------------
    const int d = d0 + lane;
    const int e = b * DIM + d;
    const float vf = wc[d], vr = wc[DIM + d];
    const float bfv = bias[d], brv = bias[DIM + d];
    float c = c0[e];
    float* hp = out + (size_t)b * DIM + d;

#pragma unroll 1
    for (int p = 0; p < 64; ++p) {
      __builtin_amdgcn_s_barrier();
      __builtin_amdgcn_sched_barrier(0);
      const unsigned short* sp = &Sm[p & 3][0];
      // phase 1: batch all 48 LDS reads into registers (static indices)
      unsigned u0r[16], r12r[16], xvr[16];
#pragma unroll
      for (int s = 0; s < 16; ++s) {
        u0r[s]  = sp[s * 64 + lane];
        r12r[s] = *(const unsigned*)&sp[1024 + s * 128 + lane * 2];
        xvr[s]  = sp[3072 + s * 64 + lane];
      }
      // phase 2: serial recurrence, register-only (compiler places lgkm waits)
#pragma unroll
      for (int s = 0; s < 16; ++s) {
        const float a0 = __uint_as_float(u0r[s] << 16);
        const float u1 = __uint_as_float(r12r[s] << 16);
        const float u2 = __uint_as_float(r12r[s] & 0xFFFF0000u);
        const float ax = __uint_as_float(xvr[s] << 16) * SCALE_X;
        const float fg = sigmoidf_fast(u1 + fmaf(vf, c, bfv));
        c = fmaf(c - a0, fg, a0);
        const float rr = sigmoidf_fast(u2 + fmaf(vr, c, brv));
        __builtin_nontemporal_store(fmaf(rr, c - ax, ax), hp);
        hp += XS;
      }
      LGKM0;  // all slot reads complete before passing the next barrier
    }
    out[(size_t)L_SEQ * XS + e] = c;
  }
}

// --------------------------------- launcher ------------------------------------
extern "C" void kernel_launch(void* const* d_in, const int* in_sizes, int n_in,
                              void* d_out, int out_size, void* d_ws, size_t ws_size,
                              hipStream_t stream) {
  const float* x    = (const float*)d_in[0];
  const float* c0   = (const float*)d_in[1];
  const float* W    = (const float*)d_in[2];
  const float* wc   = (const float*)d_in[3];
  const float* bias = (const float*)d_in[4];
  float* out = (float*)d_out;

  char* ws = (char*)d_ws;
  // flat layout: A 33,554,432 (+512K pad) | Bt 25,165,824 | U 100,663,296 (+pad)
  unsigned short* A_bf  = (unsigned short*)(ws);
  unsigned short* Bt_bf = (unsigned short*)(ws + 34078720);
  unsigned short* U_bf  = (unsigned short*)(ws + 59244544);

  prep_kernel<<<4864, 256, 0, stream>>>((const float4*)x, A_bf, W, Bt_bf);
  gemm_kernel<<<dim3(GN / BN, GM / BM), 512, 0, stream>>>(A_bf, Bt_bf, U_bf);
  sru_scan_pc<<<256, 128, 0, stream>>>(U_bf, A_bf, c0, wc, bias, out);
}

// Round 17
// 387.358 us; speedup vs baseline: 1.0293x; 1.0293x over previous
//
#include <hip/hip_runtime.h>
#include <stdint.h>

// Problem constants (fixed by reference: L=1024, B=8, D=2048)
#define L_SEQ 1024
#define BATCH 8
#define DIM   2048
#define GM    8192   // L*B
#define GN    6144   // 3*D
#define GK    2048   // D
#define SCALE_X 1.7320508075688772f  // sqrt(1 + 2*exp(0))

// GEMM geometry: 256x256 tile, 8 waves (2M x 4N), k-ring of 4 slices of 32
#define BM 256
#define BN 256
#define BKC 32

using bf16x8  = __attribute__((ext_vector_type(8))) __bf16;
using floatx4 = __attribute__((ext_vector_type(4))) float;

__device__ __forceinline__ unsigned short f2bf(float f) {
  unsigned u = __float_as_uint(f);
  u += 0x7FFFu + ((u >> 16) & 1u);   // round-to-nearest-even
  return (unsigned short)(u >> 16);
}
__device__ __forceinline__ float sigmoidf_fast(float z) {
  return __builtin_amdgcn_rcpf(1.0f + __expf(-z));
}
__device__ __forceinline__ void async16(const unsigned short* g, unsigned short* l) {
  __builtin_amdgcn_global_load_lds(
      (__attribute__((address_space(1))) unsigned int*)g,
      (__attribute__((address_space(3))) unsigned int*)l,
      16, 0, 0);
}

// ------------- fused prep: transpose-cast W -> Bt  +  cast x -> A (bf16) --------
// r8/r14 version (part of the 392us best run). Blocks [0, 3072): 64x64
// transpose tiles (n-tile = blk%96, k-tile = blk/96). Reads W via float4;
// writes Bt rows as 8x 16B ushort8 chunks -> each 8-thread group covers one
// full 128-B line (no partial-line RMW). Blocks [3072, 7168): grid-stride
// streaming cast of x.
// W col n = 3d+j -> j==0: Bt row d (u0 plane); j>0: Bt row DIM + 2d + (j-1).
__global__ __launch_bounds__(256) void prep_kernel(const float4* __restrict__ xin,
                                                   unsigned short* __restrict__ Aout,
                                                   const float* __restrict__ W,
                                                   unsigned short* __restrict__ Bt) {
  __shared__ float tile[64][65];
  const int blk = blockIdx.x;
  if (blk < 3072) {
    const int tx = threadIdx.x & 15, ty = threadIdx.x >> 4;
    const int n0 = (blk % 96) * 64;
    const int k0 = (blk / 96) * 64;
#pragma unroll
    for (int p = 0; p < 4; ++p) {
      const float4 v = *(const float4*)&W[(size_t)(k0 + ty + 16 * p) * GN + n0 + tx * 4];
      float* t = &tile[ty + 16 * p][tx * 4];
      t[0] = v.x; t[1] = v.y; t[2] = v.z; t[3] = v.w;
    }
    __syncthreads();
#pragma unroll
    for (int p = 0; p < 2; ++p) {
      const int jl = (threadIdx.x >> 3) + 32 * p;          // 0..63 n-local
      const int n = n0 + jl;
      const int dq = n / 3, j3 = n - 3 * dq;
      const int np = (j3 == 0) ? dq : (DIM + 2 * dq + (j3 - 1));
      const int klb = (threadIdx.x & 7) * 8;               // 0..56 k-local
      union { unsigned short s[8]; uint4 q; } o;
#pragma unroll
      for (int kk = 0; kk < 8; ++kk) o.s[kk] = f2bf(tile[klb + kk][jl]);
      *(uint4*)&Bt[(size_t)np * GK + k0 + klb] = o.q;
    }
  } else {
    const int n4 = (GM * GK) / 4;
    for (int i = (blk - 3072) * 256 + threadIdx.x; i < n4; i += 4096 * 256) {
      float4 v = xin[i];
      union { unsigned short s[4]; unsigned long long ll; } o;
      o.s[0] = f2bf(v.x); o.s[1] = f2bf(v.y); o.s[2] = f2bf(v.z); o.s[3] = f2bf(v.w);
      *(unsigned long long*)&Aout[(size_t)i * 4] = o.ll;
    }
  }
}

// ---------------- GEMM: U = A(GM x GK) * Bt(GN x GK)^T, bf16 out ----------------
// Round-4/8 structure verbatim (best measured: 197-200us, MfmaUtil 46, conf 0).
// Merged-body attempts (r5, r13), BN=384 (r11), 32x32 MFMA (r6) all regressed
// -> this is the structure's floor. 256x256 tile, 8 waves (2M x 4N), per-wave
// 128x64 = 8x4 reps of 16x16x32 MFMA. LDS = ring of 4 k-slices: 128 KB.
// Per chunk c: WAITV(8) ; BAR0 ; R0(8 ds_read) + stageA(c+3) ; BAR1 ; lgkm0 ;
// 16 MFMA ; BAR2 ; R1(4 ds_read) + stageB(c+3) ; BAR3 ; lgkm0 ; 16 MFMA.
// WAITV(8) waits only chunk c's loads (issued 3 chunks earlier -> free).
// LDS swizzle: 16B slot S(row,s) = (row>>1)*8 + (((row&1)*4+s)^((row>>1)&7));
// read-side XOR + inverse-permuted global source (LDS dest lane-linear).
// XCD-rectangle swizzle: 768 = 8 XCD x 3 rounds x (4y x 8x).

#define WAITV(N) asm volatile("s_waitcnt vmcnt(" #N ")" ::: "memory")
#define LGKM0 asm volatile("s_waitcnt lgkmcnt(0)" ::: "memory"); \
              __builtin_amdgcn_sched_barrier(0)

#define CHUNK(cexpr, SL, DOSTAGE)                                             \
  {                                                                           \
    __builtin_amdgcn_s_barrier();  /* BAR0 */                                 \
    __builtin_amdgcn_sched_barrier(0);                                        \
    const int c_ = (cexpr);                                                   \
    const char* aB_ = AsB + (SL) * 16384;                                     \
    const char* bB_ = BsB + (SL) * 16384;                                     \
    bf16x8 bF[4], aF[4];                                                      \
    _Pragma("unroll") for (int nt = 0; nt < 4; ++nt)                          \
        bF[nt] = *(const bf16x8*)(bB_ + SB0 + nt * 1024);                     \
    _Pragma("unroll") for (int mt = 0; mt < 4; ++mt)                          \
        aF[mt] = *(const bf16x8*)(aB_ + SA0 + mt * 1024);                     \
    if (DOSTAGE) {                                                            \
      unsigned short* ad_ = (unsigned short*)(AsL + ((c_ + 3) & 3) * 16384);  \
      const int ko_ = (c_ + 3) * BKC;                                         \
      async16(aG0 + ko_, ad_ + L0 * 8);                                       \
      async16(aG1 + ko_, ad_ + L1 * 8);                                       \
    }                                                                         \
    __builtin_amdgcn_sched_barrier(0);                                        \
    __builtin_amdgcn_s_barrier();  /* BAR1: read-burst | MFMA-burst fence */  \
    LGKM0;                                                                    \
    __builtin_amdgcn_s_setprio(1);                                            \
    _Pragma("unroll") for (int mt = 0; mt < 4; ++mt)                          \
      _Pragma("unroll") for (int nt = 0; nt < 4; ++nt)                        \
        acc[mt][nt] = __builtin_amdgcn_mfma_f32_16x16x32_bf16(                \
            aF[mt], bF[nt], acc[mt][nt], 0, 0, 0);                            \
    __builtin_amdgcn_s_setprio(0);                                            \
    __builtin_amdgcn_sched_barrier(0);                                        \
    __builtin_amdgcn_s_barrier();  /* BAR2 */                                 \
    _Pragma("unroll") for (int mt = 0; mt < 4; ++mt)                          \
        aF[mt] = *(const bf16x8*)(aB_ + SA0 + 4096 + mt * 1024);              \
    if (DOSTAGE) {                                                            \
      unsigned short* bd_ = (unsigned short*)(BsL + ((c_ + 3) & 3) * 16384);  \
      const int ko_ = (c_ + 3) * BKC;                                        \
      async16(bG0 + ko_, bd_ + L0 * 8);                                       \
      async16(bG1 + ko_, bd_ + L1 * 8);                                       \
    }                                                                         \
    __builtin_amdgcn_sched_barrier(0);                                        \
    __builtin_amdgcn_s_barrier();  /* BAR3 */                                 \
    LGKM0;                                                                    \
    __builtin_amdgcn_s_setprio(1);                                            \
    _Pragma("unroll") for (int mt = 0; mt < 4; ++mt)                          \
      _Pragma("unroll") for (int nt = 0; nt < 4; ++nt)                        \
        acc[mt + 4][nt] = __builtin_amdgcn_mfma_f32_16x16x32_bf16(            \
            aF[mt], bF[nt], acc[mt + 4][nt], 0, 0, 0);                        \
    __builtin_amdgcn_s_setprio(0);                                            \
    __builtin_amdgcn_sched_barrier(0);                                        \
  }

__global__ __launch_bounds__(512, 2) void gemm_kernel(const unsigned short* __restrict__ A,
                                                      const unsigned short* __restrict__ Bt,
                                                      unsigned short* __restrict__ U) {
  __shared__ alignas(16) unsigned short As[4][BM * BKC];  // 64 KB
  __shared__ alignas(16) unsigned short Bs[4][BN * BKC];  // 64 KB
  const int tid  = threadIdx.x;
  const int wave = tid >> 6, lane = tid & 63;
  const int quad = lane >> 4, lrow = lane & 15;
  const int wm = (wave >> 2) * 128;  // 2 M-waves
  const int wn = (wave & 3) * 64;    // 4 N-waves

  // XCD-rectangle swizzle: 768 blocks = 8 XCD x 3 rounds x 32 slots (4y x 8x)
  const int f    = blockIdx.y * (GN / BN) + blockIdx.x;
  const int xcd  = f & 7;
  const int slot = f >> 3;
  const int rnd  = slot >> 5;        // 0..2
  const int ss   = slot & 31;        // 0..31
  const int mBase = (4 * xcd + (ss & 3)) * BM;   // y-tile 0..31
  const int nBase = (8 * rnd + (ss >> 2)) * BN;  // x-tile 0..23

  floatx4 acc[8][4] = {};

  // staging: thread owns 16B slots L0=tid, L1=tid+512 of each slice (lane-linear
  // LDS dest). Invert swizzle to find the (row, k-slot) this slot must hold.
  const int L0 = tid, L1 = tid + 512;
  int r0, s0, r1, s1;
  { const int p = L0 >> 3, w = L0 & 7, v = w ^ (p & 7); r0 = 2 * p + (v >> 2); s0 = v & 3; }
  { const int p = L1 >> 3, w = L1 & 7, v = w ^ (p & 7); r1 = 2 * p + (v >> 2); s1 = v & 3; }
  const unsigned short* aG0 = A  + (size_t)(mBase + r0) * GK + s0 * 8;
  const unsigned short* aG1 = A  + (size_t)(mBase + r1) * GK + s1 * 8;
  const unsigned short* bG0 = Bt + (size_t)(nBase + r0) * GK + s0 * 8;
  const unsigned short* bG1 = Bt + (size_t)(nBase + r1) * GK + s1 * 8;

  // ds_read byte offsets within a slice (+16 rows = +1024 B)
  const int rA = wm + lrow;
  const int SA0 = (rA >> 1) * 128 + ((((rA & 1) * 4 + quad) ^ ((rA >> 1) & 7)) * 16);
  const int rB = wn + lrow;
  const int SB0 = (rB >> 1) * 128 + ((((rB & 1) * 4 + quad) ^ ((rB >> 1) & 7)) * 16);
  const char* AsB = (const char*)As;
  const char* BsB = (const char*)Bs;
  char* AsL = (char*)As;
  char* BsL = (char*)Bs;

  // prologue: stage chunks 0,1,2 (12 loads/thread in flight)
#pragma unroll
  for (int c = 0; c < 3; ++c) {
    unsigned short* ad = (unsigned short*)(AsL + c * 16384);
    unsigned short* bd = (unsigned short*)(BsL + c * 16384);
    async16(aG0 + c * BKC, ad + L0 * 8);
    async16(aG1 + c * BKC, ad + L1 * 8);
    async16(bG0 + c * BKC, bd + L0 * 8);
    async16(bG1 + c * BKC, bd + L1 * 8);
  }

  // main loop: chunks 0..59 (stage c+3), then peeled 60..63
#pragma unroll 1
  for (int cc = 0; cc < 15; ++cc) {
    const int cb = cc * 4;
#pragma unroll
    for (int j = 0; j < 4; ++j) {
      WAITV(8);
      CHUNK(cb + j, j, true);
    }
  }
  WAITV(8); CHUNK(60, 0, true);   // stages chunk 63
  WAITV(8); CHUNK(61, 1, false);
  WAITV(4); CHUNK(62, 2, false);
  WAITV(0); CHUNK(63, 3, false);

  // C/D layout: col = lane&15 (N), row = quad*4 + reg (M). Flat U: col = gn.
#pragma unroll
  for (int mt = 0; mt < 8; ++mt) {
    const int gm = mBase + wm + mt * 16 + quad * 4;
#pragma unroll
    for (int nt = 0; nt < 4; ++nt) {
      const int gn = nBase + wn + nt * 16 + lrow;
#pragma unroll
      for (int q = 0; q < 4; ++q)
        U[(size_t)(gm + q) * GN + gn] = f2bf(acc[mt][nt][q]);
    }
  }
}

// ------------- SRU scan: producer/consumer wave split over an LDS ring ----------
// r14 version verbatim (benched 392us, session best). 256 blocks x 128 threads.
// Wave 1 (producer): 4-slot x 16-step LDS ring, 8 global_load_lds dwordx4 per
// slot. WAITV(16) seals slot p+1; slot p+3 overwrites slot p-1.
// Wave 0 (consumer): hoists all 48 LDS reads of the phase into registers
// (static indexing) before the serial math loop, then runs the recurrence
// register-only. Same ops/order -> bit-identical output.
__global__ __launch_bounds__(128) void sru_scan_pc(const unsigned short* __restrict__ U,
                                                   const unsigned short* __restrict__ xbf,
                                                   const float* __restrict__ c0,
                                                   const float* __restrict__ wc,
                                                   const float* __restrict__ bias,
                                                   float* __restrict__ out) {
  __shared__ alignas(16) unsigned short Sm[4][4096];  // 4 slots x 8 KB
  const int tid  = threadIdx.x;
  const int wave = tid >> 6, lane = tid & 63;
  const int blk = blockIdx.x;
  const int b = blk >> 5, dch = blk & 31;
  const int d0 = dch * 64;

  constexpr size_t US  = (size_t)BATCH * GN;   // shorts per l-step (U)
  constexpr size_t XSs = (size_t)BATCH * DIM;  // shorts per l-step (x)
  constexpr int XS = BATCH * DIM;              // floats per l-step (out)

  if (wave == 1) {
    // ---------------- producer ----------------
    const int s8 = lane >> 3, c8 = lane & 7;    // 8-step groups (u0, x)
    const int s4 = lane >> 4, c16 = lane & 15;  // 4-step groups (u1u2)
    const unsigned short* u0g  = U   + (size_t)b * GN + d0 + c8 * 8 + (size_t)s8 * US;
    const unsigned short* u12g = U   + (size_t)b * GN + DIM + 2 * d0 + c16 * 8 + (size_t)s4 * US;
    const unsigned short* xg   = xbf + (size_t)b * DIM + d0 + c8 * 8 + (size_t)s8 * XSs;

#define STAGE_SLOT(SL, L0S)                                                   \
    {                                                                         \
      unsigned short* dst = &Sm[(SL)][0] + lane * 8;                          \
      const size_t l0_ = (size_t)(L0S);                                       \
      async16(u0g + l0_ * US, dst);              /* steps l0..l0+7   */       \
      async16(u0g + (l0_ + 8) * US, dst + 512);  /* steps l0+8..+15  */       \
      async16(u12g + l0_ * US, dst + 1024);      /* steps l0..l0+3   */       \
      async16(u12g + (l0_ + 4) * US, dst + 1536);                             \
      async16(u12g + (l0_ + 8) * US, dst + 2048);                             \
      async16(u12g + (l0_ + 12) * US, dst + 2560);                            \
      async16(xg + l0_ * XSs, dst + 3072);                                    \
      async16(xg + (l0_ + 8) * XSs, dst + 3584);                              \
    }

    // prologue: slots 0,1,2 (24 in flight); seal slot 0
    STAGE_SLOT(0, 0); STAGE_SLOT(1, 16); STAGE_SLOT(2, 32);
    WAITV(16);
#pragma unroll 1
    for (int p = 0; p < 64; ++p) {
      __builtin_amdgcn_s_barrier();
      __builtin_amdgcn_sched_barrier(0);
      if (p < 61) {
        STAGE_SLOT((p + 3) & 3, 16 * (p + 3));
        WAITV(16);           // seal slot p+1; keep p+2, p+3 in flight
      } else if (p == 61) {
        WAITV(8);            // seal slot 62
      } else if (p == 62) {
        WAITV(0);            // seal slot 63
      }
      __builtin_amdgcn_sched_barrier(0);
    }
#undef STAGE_SLOT
  } else {
    // ---------------- consumer ----------------
    const int d = d0 + lane;
    const int e = b * DIM + d;
    const float vf = wc[d], vr = wc[DIM + d];
    const float bfv = bias[d], brv = bias[DIM + d];
    float c = c0[e];
    float* hp = out + (size_t)b * DIM + d;

#pragma unroll 1
    for (int p = 0; p < 64; ++p) {
      __builtin_amdgcn_s_barrier();
      __builtin_amdgcn_sched_barrier(0);
      const unsigned short* sp = &Sm[p & 3][0];
      // phase 1: batch all 48 LDS reads into registers (static indices)
      unsigned u0r[16], r12r[16], xvr[16];
#pragma unroll
      for (int s = 0; s < 16; ++s) {
        u0r[s]  = sp[s * 64 + lane];
        r12r[s] = *(const unsigned*)&sp[1024 + s * 128 + lane * 2];
        xvr[s]  = sp[3072 + s * 64 + lane];
      }
      // phase 2: serial recurrence, register-only (compiler places lgkm waits)
#pragma unroll
      for (int s = 0; s < 16; ++s) {
        const float a0 = __uint_as_float(u0r[s] << 16);
        const float u1 = __uint_as_float(r12r[s] << 16);
        const float u2 = __uint_as_float(r12r[s] & 0xFFFF0000u);
        const float ax = __uint_as_float(xvr[s] << 16) * SCALE_X;
        const float fg = sigmoidf_fast(u1 + fmaf(vf, c, bfv));
        c = fmaf(c - a0, fg, a0);
        const float rr = sigmoidf_fast(u2 + fmaf(vr, c, brv));
        __builtin_nontemporal_store(fmaf(rr, c - ax, ax), hp);
        hp += XS;
      }
      LGKM0;  // all slot reads complete before passing the next barrier
    }
    out[(size_t)L_SEQ * XS + e] = c;
  }
}

// --------------------------------- launcher ------------------------------------
extern "C" void kernel_launch(void* const* d_in, const int* in_sizes, int n_in,
                              void* d_out, int out_size, void* d_ws, size_t ws_size,
                              hipStream_t stream) {
  const float* x    = (const float*)d_in[0];
  const float* c0   = (const float*)d_in[1];
  const float* W    = (const float*)d_in[2];
  const float* wc   = (const float*)d_in[3];
  const float* bias = (const float*)d_in[4];
  float* out = (float*)d_out;

  char* ws = (char*)d_ws;
  // flat layout: A 33,554,432 (+512K pad) | Bt 25,165,824 | U 100,663,296 (+pad)
  unsigned short* A_bf  = (unsigned short*)(ws);
  unsigned short* Bt_bf = (unsigned short*)(ws + 34078720);
  unsigned short* U_bf  = (unsigned short*)(ws + 59244544);

  prep_kernel<<<7168, 256, 0, stream>>>((const float4*)x, A_bf, W, Bt_bf);
  gemm_kernel<<<dim3(GN / BN, GM / BM), 512, 0, stream>>>(A_bf, Bt_bf, U_bf);
  sru_scan_pc<<<256, 128, 0, stream>>>(U_bf, A_bf, c0, wc, bias, out);
}